// Round 14
// baseline (213.293 us; speedup 1.0000x reference)
//
#include <hip/hip_runtime.h>
#include <math.h>

#define H_DIM 256
#define HEADS 4
#define HD 64
#define TOPK 15
#define NSLOPE 0.2
#define NSLOPEF 0.2f
#define EDGE_CAP_MAX 128
#define CAND_CAP 256
#define RPB 4

// prep1: 16 blocks. All zero cnt (4096 ints); blocks 0..7 compute wa for
// (head = b>>1, side = b&1); block 8 packs active[] into 4096-bit abits.
__global__ __launch_bounds__(256) void prep1_kernel(const float* __restrict__ W,
                                                    const float* __restrict__ att,
                                                    double* __restrict__ wa_dst,
                                                    double* __restrict__ wa_src,
                                                    int* __restrict__ cnt,
                                                    unsigned int* __restrict__ abits,
                                                    const int* __restrict__ active) {
    const int b = blockIdx.x;
    cnt[b * 256 + threadIdx.x] = 0;
    if (b < 2 * HEADS) {
        const int k = threadIdx.x;
        const int h = b >> 1;
        const int side = b & 1;
        double a = 0.0;
        for (int d = 0; d < HD; ++d)
            a += (double)W[(h * HD + d) * H_DIM + k] * (double)att[h * 2 * HD + side * HD + d];
        (side ? wa_src : wa_dst)[h * H_DIM + k] = a;
    } else if (b == 8 && threadIdx.x < 128) {
        const int* ap = active + threadIdx.x * 32;
        unsigned int wv = 0;
        for (int t = 0; t < 32; ++t)
            if (ap[t]) wv |= 1u << t;
        abits[threadIdx.x] = wv;
    }
}

// prep2: fused independent stages, partitioned by blockIdx:
//   [0, 1024)        s-compute: one wave per row (writes fp64 + fp32 copies)
//   [1024, 1024+nb)  edge-table build: one int4 {col,eid,w_bits,0} per edge
__global__ __launch_bounds__(256) void prep2_kernel(
    const float* __restrict__ emb, const double* __restrict__ wa_dst,
    const double* __restrict__ wa_src, double* __restrict__ s_dst,
    double* __restrict__ s_src, float* __restrict__ s_dst_f,
    float* __restrict__ s_src_f, const int* __restrict__ eidx,
    const float* __restrict__ ew, int* __restrict__ cnt,
    int4* __restrict__ etab, int N, int E, int cap) {
    const int b = blockIdx.x;
    const int tid = threadIdx.x;

    if (b < 1024) {
        // ---- s-compute ----
        const int lane = tid & 63;
        const int wid = tid >> 6;
        const int i = b * 4 + wid;
        double e[4];
#pragma unroll
        for (int m = 0; m < 4; ++m) e[m] = (double)emb[(size_t)i * H_DIM + lane + 64 * m];
        double acc[8];
#pragma unroll
        for (int c = 0; c < 8; ++c) {
            const double* wa = (c & 1) ? wa_src : wa_dst;
            const int h = c >> 1;
            double a = 0.0;
#pragma unroll
            for (int m = 0; m < 4; ++m) a += e[m] * wa[h * H_DIM + lane + 64 * m];
            acc[c] = a;
        }
#pragma unroll
        for (int m = 1; m < 64; m <<= 1) {
#pragma unroll
            for (int c = 0; c < 8; ++c) acc[c] += __shfl_xor(acc[c], m, 64);
        }
        if (lane == 0) {
#pragma unroll
            for (int c = 0; c < 8; ++c) {
                const int h = c >> 1;
                if (c & 1) {
                    s_src[i * HEADS + h] = acc[c];
                    s_src_f[i * HEADS + h] = (float)acc[c];
                } else {
                    s_dst[i * HEADS + h] = acc[c];
                    s_dst_f[i * HEADS + h] = (float)acc[c];
                }
            }
        }
    } else {
        // ---- edge-table build (slot order nondeterministic; dedup is by max
        // edge id, which is order-independent) ----
        const int e = (b - 1024) * 256 + tid;
        if (e < E) {
            const int r = eidx[e];
            const int c = eidx[E + e];
            const int s = atomicAdd(&cnt[r], 1);
            if (s < cap) {
                int4 rec;
                rec.x = c;
                rec.y = e;
                rec.z = __float_as_int(ew[e]);
                rec.w = 0;
                etab[r * cap + s] = rec;
            }
        }
    }
}

#define FOR16(OP) OP(0) OP(1) OP(2) OP(3) OP(4) OP(5) OP(6) OP(7) \
                  OP(8) OP(9) OP(10) OP(11) OP(12) OP(13) OP(14) OP(15)

// 4 rows per block (grid = N/4): tests the per-workgroup-overhead hypothesis.
// Per row, structure identical to R13: wave-local ownership j =
// (wid<<10)|(k<<6)|lane, mask bit-transpose via 16 intra-wave shuffles,
// fp32 selection (ballot threshold relaxed 256 ulp -> provable superset),
// exact fp64 re-rank by (value, index) -> output identical to all-fp64.
__global__ __launch_bounds__(256) void main_kernel(
    const double* __restrict__ s_dst, const double* __restrict__ s_src,
    const float* __restrict__ s_dst_f, const float* __restrict__ s_src_f,
    const int* __restrict__ sector_mask, const unsigned short* __restrict__ abits16,
    const int* __restrict__ active, const float* __restrict__ lam_p,
    const int* __restrict__ cnt, const int4* __restrict__ etab,
    float* __restrict__ out, int N, int cap) {
    const int b = blockIdx.x;
    const int tid = threadIdx.x;
    const int lane = tid & 63;
    const int wid = tid >> 6;

    __shared__ int ec[RPB][EDGE_CAP_MAX];
    __shared__ int ee[RPB][EDGE_CAP_MAX];
    __shared__ float ewl[RPB][EDGE_CAP_MAX];
    __shared__ int degS[RPB];
    __shared__ int wcol[EDGE_CAP_MAX];
    __shared__ double wadd[EDGE_CAP_MAX];   // fp64 winner add (exact re-rank)
    __shared__ unsigned int wth[4];
    __shared__ double cand_v[CAND_CAP];
    __shared__ int cand_i[CAND_CAP];
    __shared__ int cand_cnt, wcnt;
    __shared__ double sorted_v[TOPK];
    __shared__ int sorted_i[TOPK];
    __shared__ double exps[TOPK];

    // Stage all 4 rows' edge slices once
    if (tid < RPB) degS[tid] = min(cnt[b * RPB + tid], cap);
#pragma unroll 1
    for (int r = 0; r < RPB; ++r) {
        const int i = b * RPB + r;
        const int d = min(cnt[i], cap);
        for (int p = tid; p < d; p += 256) {
            const int4 rec = etab[i * cap + p];
            ec[r][p] = rec.x;
            ee[r][p] = rec.y;
            ewl[r][p] = __int_as_float(rec.z);
        }
    }

    const unsigned int act_us = (unsigned int)abits16[tid];
    const double lam = (double)lam_p[0];
    const double4* __restrict__ s_src4 = (const double4*)s_src;
    const float4* __restrict__ s_srcf4 = (const float4*)s_src_f;
    const int jbase = (wid << 10) | lane;  // owned column for k: jbase + (k<<6)
    const int lhi = lane >> 4;
    const int llo = lane & 15;

#pragma unroll 1
    for (int r = 0; r < RPB; ++r) {
        const int i = b * RPB + r;
        const int deg = degS[r];

        __syncthreads();  // staging (r==0) / prev row's shared reads done
        if (tid == 0) { cand_cnt = 0; wcnt = 0; }

        // Coalesced mask-row read (64 B/thread) + AND with active slice;
        // consumed via registers/shuffles only.
        const int* mrow = sector_mask + (size_t)i * N;
        const int4 m0 = *(const int4*)(mrow + 16 * tid);
        const int4 m1 = *(const int4*)(mrow + 16 * tid + 4);
        const int4 m2 = *(const int4*)(mrow + 16 * tid + 8);
        const int4 m3 = *(const int4*)(mrow + 16 * tid + 12);
        unsigned int pb = 0;
#define PB(C, VAL) if ((VAL) != 0) pb |= (1u << (C));
        PB(0, m0.x)  PB(1, m0.y)  PB(2, m0.z)  PB(3, m0.w)
        PB(4, m1.x)  PB(5, m1.y)  PB(6, m1.z)  PB(7, m1.w)
        PB(8, m2.x)  PB(9, m2.y)  PB(10, m2.z) PB(11, m2.w)
        PB(12, m3.x) PB(13, m3.y) PB(14, m3.z) PB(15, m3.w)
#undef PB
        pb &= act_us;

        // Intra-wave bit-transpose: col j=(wid<<10)|(k<<6)|lane was loaded by
        // lane 4k+(lane>>4) of the SAME wave, bit (lane&15) of its pb.
        unsigned int pm = 0;
#pragma unroll
        for (int k = 0; k < 16; ++k) {
            const unsigned int opb = (unsigned int)__shfl((int)pb, 4 * k + lhi, 64);
            pm |= ((opb >> llo) & 1u) << k;
        }
        if (active[i] == 0) pm = 0;

        // fp32 sd for selection; fp64 sd for exact re-rank
        const float sdf0 = s_dst_f[i * 4 + 0];
        const float sdf1 = s_dst_f[i * 4 + 1];
        const float sdf2 = s_dst_f[i * 4 + 2];
        const float sdf3 = s_dst_f[i * 4 + 3];
        const double sd0 = s_dst[i * 4 + 0];
        const double sd1 = s_dst[i * 4 + 1];
        const double sd2 = s_dst[i * 4 + 2];
        const double sd3 = s_dst[i * 4 + 3];

        // Phase 1 (fp32): scores into 16 named registers (coalesced per-wave)
        float f0, f1, f2, f3, f4, f5, f6, f7, f8, f9, f10, f11, f12, f13, f14, f15;
#define INIT_SLOT(K) { \
    const bool m = (pm >> K) & 1u; \
    const float4 sv = s_srcf4[jbase + (K << 6)]; \
    float x0 = sdf0 + sv.x, x1 = sdf1 + sv.y, x2 = sdf2 + sv.z, x3 = sdf3 + sv.w; \
    x0 = (x0 < 0.0f) ? NSLOPEF * x0 : x0; \
    x1 = (x1 < 0.0f) ? NSLOPEF * x1 : x1; \
    x2 = (x2 < 0.0f) ? NSLOPEF * x2 : x2; \
    x3 = (x3 < 0.0f) ? NSLOPEF * x3 : x3; \
    f##K = m ? (0.25f * (x0 + x1 + x2 + x3)) : -INFINITY; }
        FOR16(INIT_SLOT)
#undef INIT_SLOT

        __syncthreads();  // cand_cnt/wcnt resets visible

        // Phase 2a: parallel dedup (last-write-wins by edge id)
        if (tid < deg) {
            const int c = ec[r][tid];
            const int eid = ee[r][tid];
            bool win = true;
            for (int q = 0; q < deg; ++q)
                if (ec[r][q] == c && ee[r][q] > eid) win = false;
            if (win) {
                int p = atomicAdd(&wcnt, 1);
                wcol[p] = c;
                wadd[p] = lam * (double)ewl[r][tid];
            }
        }
        __syncthreads();

        // Phase 2b (fp32): owner tid = ((c>>10)<<6)|(c&63) applies winner adds
        const int nw = wcnt;
        for (int w = 0; w < nw; ++w) {
            const int c = wcol[w];
            if ((((c >> 10) << 6) | (c & 63)) == tid) {
                const float addf = (float)wadd[w];
                const int kk = (c >> 6) & 15;
#define ADD_SLOT(K) if (kk == K) f##K += addf;
                FOR16(ADD_SLOT)
#undef ADD_SLOT
            }
        }

        // Phase 3a: fp32 monotone keys + per-thread local max
        unsigned int k0, k1, k2, k3, k4, k5, k6, k7, k8, k9, k10, k11, k12, k13, k14, k15;
#define KEY_SLOT(K) { const unsigned u = __float_as_uint(f##K); \
    k##K = u ^ ((unsigned)((int)u >> 31) | 0x80000000u); }
        FOR16(KEY_SLOT)
#undef KEY_SLOT
        unsigned int lmax = k0;
#define LMAX(K) if (k##K > lmax) lmax = k##K;
        FOR16(LMAX)
#undef LMAX

        // Phase 3b: per-wave 15th-largest lane-max via ballot binary search
        unsigned int th = 0;
        for (int bb = 31; bb >= 0; --bb) {
            const unsigned int trial = th | (1u << bb);
            unsigned long long m = __ballot(lmax >= trial);
            if (__popcll(m) >= TOPK) th = trial;
        }
        if (lane == 0) wth[wid] = th;
        __syncthreads();
        th = wth[0];
        if (wth[1] > th) th = wth[1];
        if (wth[2] > th) th = wth[2];
        if (wth[3] > th) th = wth[3];
        // Relax by 256 ulp: covers fp32-vs-fp64 ordering divergence at the cut.
        th = (th > 256u) ? (th - 256u) : 0u;

        // Phase 3c: candidate filter (store actual column index)
#define FILT(K) if (k##K >= th) { int p = atomicAdd(&cand_cnt, 1); \
    if (p < CAND_CAP) cand_i[p] = jbase + (K << 6); }
        FOR16(FILT)
#undef FILT
        __syncthreads();

        // Phase 4a: exact fp64 re-score of each candidate
        int C = cand_cnt;
        if (C > CAND_CAP) C = CAND_CAP;
        if (tid < C) {
            const int j = cand_i[tid];
            const double4 sv = s_src4[j];
            double x0 = sd0 + sv.x, x1 = sd1 + sv.y, x2 = sd2 + sv.z, x3 = sd3 + sv.w;
            x0 = (x0 < 0.0) ? NSLOPE * x0 : x0;
            x1 = (x1 < 0.0) ? NSLOPE * x1 : x1;
            x2 = (x2 < 0.0) ? NSLOPE * x2 : x2;
            x3 = (x3 < 0.0) ? NSLOPE * x3 : x3;
            double v = 0.25 * (x0 + x1 + x2 + x3);
            for (int w = 0; w < nw; ++w)
                if (wcol[w] == j) v += wadd[w];
            cand_v[tid] = v;
        }
        __syncthreads();

        // Phase 4b: exact fp64 rank-by-counting (unique ranks)
        if (tid < C) {
            const double mv = cand_v[tid];
            const int mi = cand_i[tid];
            int rank = 0;
            for (int q = 0; q < C; ++q) {
                const double qv = cand_v[q];
                const int qi = cand_i[q];
                rank += ((qv > mv) || (qv == mv && qi < mi)) ? 1 : 0;
            }
            if (rank < TOPK) { sorted_v[rank] = mv; sorted_i[rank] = mi; }
        }
        __syncthreads();

        // Phase 5: softmax + store (fp64)
        if (tid < TOPK) exps[tid] = exp(sorted_v[tid] - sorted_v[0]);
        __syncthreads();
        if (tid < TOPK) {
            double s = 0.0;
            for (int t = 0; t < TOPK; ++t) s += exps[t];
            const int NK = N * TOPK;
            const int base = i * TOPK + tid;
            out[base] = (float)sorted_i[tid];
            out[NK + base] = (float)i;
            out[2 * NK + base] = (float)(exps[tid] / s);
        }
    }
}

extern "C" void kernel_launch(void* const* d_in, const int* in_sizes, int n_in,
                              void* d_out, int out_size, void* d_ws, size_t ws_size,
                              hipStream_t stream) {
    const float* emb    = (const float*)d_in[0];
    const float* W      = (const float*)d_in[1];
    const float* att    = (const float*)d_in[2];
    const float* lam    = (const float*)d_in[3];
    const int*   sector = (const int*)d_in[4];
    const int*   active = (const int*)d_in[5];
    const int*   eidx   = (const int*)d_in[6];
    const float* ew     = (const float*)d_in[7];
    float* out = (float*)d_out;

    const int N = in_sizes[5];      // 4096
    const int E = in_sizes[6] / 2;  // 131072

    // workspace layout
    double* wa_dst = (double*)d_ws;                       // 1024 dbl
    double* wa_src = wa_dst + HEADS * H_DIM;              // 1024 dbl
    double* s_dst  = wa_src + HEADS * H_DIM;              // N*4 dbl
    double* s_src  = s_dst + (size_t)N * HEADS;           // N*4 dbl
    float* s_dst_f = (float*)(s_src + (size_t)N * HEADS); // N*4 f32
    float* s_src_f = s_dst_f + (size_t)N * HEADS;         // N*4 f32
    int* cnt       = (int*)(s_src_f + (size_t)N * HEADS); // N int
    unsigned int* abits = (unsigned int*)(cnt + N);       // N/32 uint
    // 16B-align the edge table
    uintptr_t ep = (uintptr_t)(abits + N / 32);
    ep = (ep + 15) & ~(uintptr_t)15;
    int4* etab = (int4*)ep;

    size_t used = (ep - (uintptr_t)d_ws) + 64;
    size_t rem = (ws_size > used) ? (ws_size - used) : 0;
    int cap = (int)(rem / ((size_t)N * 16));
    if (cap > EDGE_CAP_MAX) cap = EDGE_CAP_MAX;
    if (cap < 16) cap = 16;

    const int nb = (E + 255) / 256;  // build blocks (512)

    prep1_kernel<<<16, 256, 0, stream>>>(W, att, wa_dst, wa_src, cnt, abits, active);
    prep2_kernel<<<1024 + nb, 256, 0, stream>>>(emb, wa_dst, wa_src, s_dst, s_src,
                                                s_dst_f, s_src_f, eidx, ew, cnt,
                                                etab, N, E, cap);
    main_kernel<<<N / RPB, 256, 0, stream>>>(s_dst, s_src, s_dst_f, s_src_f, sector,
                                             (const unsigned short*)abits, active, lam,
                                             cnt, etab, out, N, cap);
}

// Round 15
// 177.924 us; speedup vs baseline: 1.1988x; 1.1988x over previous
//
#include <hip/hip_runtime.h>
#include <math.h>

#define H_DIM 256
#define HEADS 4
#define HD 64
#define TOPK 15
#define NSLOPE 0.2
#define NSLOPEF 0.2f
#define EDGE_CAP_MAX 128
#define CAND_CAP 256
#define SROWS 16  // rows per s-compute block in prep2

// prep1: 16 blocks. All zero cnt (4096 ints); blocks 0..7 compute wa for
// (head = b>>1, side = b&1); block 8 packs active[] into 4096-bit abits.
__global__ __launch_bounds__(256) void prep1_kernel(const float* __restrict__ W,
                                                    const float* __restrict__ att,
                                                    double* __restrict__ wa_dst,
                                                    double* __restrict__ wa_src,
                                                    int* __restrict__ cnt,
                                                    unsigned int* __restrict__ abits,
                                                    const int* __restrict__ active) {
    const int b = blockIdx.x;
    cnt[b * 256 + threadIdx.x] = 0;
    if (b < 2 * HEADS) {
        const int k = threadIdx.x;
        const int h = b >> 1;
        const int side = b & 1;
        double a = 0.0;
        for (int d = 0; d < HD; ++d)
            a += (double)W[(h * HD + d) * H_DIM + k] * (double)att[h * 2 * HD + side * HD + d];
        (side ? wa_src : wa_dst)[h * H_DIM + k] = a;
    } else if (b == 8 && threadIdx.x < 128) {
        const int* ap = active + threadIdx.x * 32;
        unsigned int wv = 0;
        for (int t = 0; t < 32; ++t)
            if (ap[t]) wv |= 1u << t;
        abits[threadIdx.x] = wv;
    }
}

// prep2, partitioned by blockIdx:
//   [0, N/16)           s-compute: 16 rows/block, wa+emb staged in LDS once,
//                       2 threads per (row,combo) dot product (serial 128-FMA
//                       halves + one shuffle combine, fixed low+high order)
//   [N/16, N/16+nb)     edge-table build: one int4 {col,eid,w_bits,0} per edge
__global__ __launch_bounds__(256) void prep2_kernel(
    const float* __restrict__ emb, const double* __restrict__ wa_dst,
    const double* __restrict__ wa_src, double* __restrict__ s_dst,
    double* __restrict__ s_src, float* __restrict__ s_dst_f,
    float* __restrict__ s_src_f, const int* __restrict__ eidx,
    const float* __restrict__ ew, int* __restrict__ cnt,
    int4* __restrict__ etab, int N, int E, int cap, int sblocks) {
    const int b = blockIdx.x;
    const int tid = threadIdx.x;

    if (b < sblocks) {
        __shared__ double wa_l[8][258];   // +2 pad: conflict-free
        __shared__ float emb_l[SROWS][258];
        const int i0 = b * SROWS;
#pragma unroll
        for (int c = 0; c < 8; ++c)
            wa_l[c][tid] = ((c & 1) ? wa_src : wa_dst)[(c >> 1) * H_DIM + tid];
#pragma unroll
        for (int r = 0; r < SROWS; ++r)
            emb_l[r][tid] = emb[(size_t)(i0 + r) * H_DIM + tid];
        __syncthreads();

        const int j = tid >> 1;        // job 0..127: row r=j>>3, combo c=j&7
        const int half = tid & 1;      // low/high 128-element half
        const int r = j >> 3;
        const int c = j & 7;
        const int base = half * 128;
        double acc = 0.0;
#pragma unroll 8
        for (int k = 0; k < 128; ++k)
            acc += (double)emb_l[r][base + k] * wa_l[c][base + k];
        const double other = __shfl_xor(acc, 1, 64);
        const double lo = half ? other : acc;
        const double hi = half ? acc : other;
        const double s = lo + hi;      // fixed order: low half + high half
        if (half == 0) {
            const int i = i0 + r;
            const int h = c >> 1;
            if (c & 1) {
                s_src[i * HEADS + h] = s;
                s_src_f[i * HEADS + h] = (float)s;
            } else {
                s_dst[i * HEADS + h] = s;
                s_dst_f[i * HEADS + h] = (float)s;
            }
        }
    } else {
        // ---- edge-table build (slot order nondeterministic; dedup is by max
        // edge id, which is order-independent) ----
        const int e = (b - sblocks) * 256 + tid;
        if (e < E) {
            const int r = eidx[e];
            const int cc = eidx[E + e];
            const int s = atomicAdd(&cnt[r], 1);
            if (s < cap) {
                int4 rec;
                rec.x = cc;
                rec.y = e;
                rec.z = __float_as_int(ew[e]);
                rec.w = 0;
                etab[r * cap + s] = rec;
            }
        }
    }
}

#define FOR16(OP) OP(0) OP(1) OP(2) OP(3) OP(4) OP(5) OP(6) OP(7) \
                  OP(8) OP(9) OP(10) OP(11) OP(12) OP(13) OP(14) OP(15)

// One block per row (R13 structure, proven 70 us / VGPR 24 / occ ~71%).
// Wave-local ownership: thread (wave w, lane l) owns columns
// j = (w<<10)|(k<<6)|l; mask bit-transpose via 16 intra-wave shuffles (no
// LDS, no barrier on the mask path). fp32 selection (ballot threshold
// relaxed 256 ulp -> provable superset); exact fp64 re-rank by (value, index).
__global__ __launch_bounds__(256) void main_kernel(
    const double* __restrict__ s_dst, const double* __restrict__ s_src,
    const float* __restrict__ s_dst_f, const float* __restrict__ s_src_f,
    const int* __restrict__ sector_mask, const unsigned short* __restrict__ abits16,
    const int* __restrict__ active, const float* __restrict__ lam_p,
    const int* __restrict__ cnt, const int4* __restrict__ etab,
    float* __restrict__ out, int N, int cap) {
    const int i = blockIdx.x;
    const int tid = threadIdx.x;
    const int lane = tid & 63;
    const int wid = tid >> 6;

    __shared__ int ec[EDGE_CAP_MAX];
    __shared__ int ee[EDGE_CAP_MAX];
    __shared__ float ewl[EDGE_CAP_MAX];
    __shared__ int wcol[EDGE_CAP_MAX];
    __shared__ double wadd[EDGE_CAP_MAX];   // fp64 winner add (exact re-rank)
    __shared__ unsigned int wth[4];
    __shared__ double cand_v[CAND_CAP];
    __shared__ int cand_i[CAND_CAP];
    __shared__ int cand_cnt, wcnt;
    __shared__ double sorted_v[TOPK];
    __shared__ int sorted_i[TOPK];
    __shared__ double exps[TOPK];

    if (tid == 0) { cand_cnt = 0; wcnt = 0; }

    // Stage this row's edge slice: one int4 load per edge, unpacked to three
    // scalar LDS arrays. Barrier right after — only these loads drain here.
    int deg = cnt[i];
    if (deg > cap) deg = cap;
    for (int p = tid; p < deg; p += 256) {
        const int4 rec = etab[i * cap + p];
        ec[p] = rec.x;
        ee[p] = rec.y;
        ewl[p] = __int_as_float(rec.z);
    }
    __syncthreads();  // edges + counters visible (cheap drain: edges only)

    // Coalesced mask-row read (64 B/thread) + AND with active ushort slice.
    // Consumed via registers/shuffles only — no barrier waits on these loads.
    const int* mrow = sector_mask + (size_t)i * N;
    const int4 m0 = *(const int4*)(mrow + 16 * tid);
    const int4 m1 = *(const int4*)(mrow + 16 * tid + 4);
    const int4 m2 = *(const int4*)(mrow + 16 * tid + 8);
    const int4 m3 = *(const int4*)(mrow + 16 * tid + 12);
    const unsigned int act_us = (unsigned int)abits16[tid];
    unsigned int pb = 0;
#define PB(C, VAL) if ((VAL) != 0) pb |= (1u << (C));
    PB(0, m0.x)  PB(1, m0.y)  PB(2, m0.z)  PB(3, m0.w)
    PB(4, m1.x)  PB(5, m1.y)  PB(6, m1.z)  PB(7, m1.w)
    PB(8, m2.x)  PB(9, m2.y)  PB(10, m2.z) PB(11, m2.w)
    PB(12, m3.x) PB(13, m3.y) PB(14, m3.z) PB(15, m3.w)
#undef PB
    pb &= act_us;

    // Intra-wave bit-transpose: col j=(wid<<10)|(k<<6)|lane was loaded by
    // lane 4k+(lane>>4) of the SAME wave, bit (lane&15) of its pb.
    const int lhi = lane >> 4;
    const int llo = lane & 15;
    unsigned int pm = 0;
#pragma unroll
    for (int k = 0; k < 16; ++k) {
        const unsigned int opb = (unsigned int)__shfl((int)pb, 4 * k + lhi, 64);
        pm |= ((opb >> llo) & 1u) << k;
    }
    if (active[i] == 0) pm = 0;

    // fp32 sd for selection; fp64 sd for exact re-rank
    const float sdf0 = s_dst_f[i * 4 + 0];
    const float sdf1 = s_dst_f[i * 4 + 1];
    const float sdf2 = s_dst_f[i * 4 + 2];
    const float sdf3 = s_dst_f[i * 4 + 3];
    const double sd0 = s_dst[i * 4 + 0];
    const double sd1 = s_dst[i * 4 + 1];
    const double sd2 = s_dst[i * 4 + 2];
    const double sd3 = s_dst[i * 4 + 3];
    const double lam = (double)lam_p[0];
    const double4* __restrict__ s_src4 = (const double4*)s_src;
    const float4* __restrict__ s_srcf4 = (const float4*)s_src_f;
    const int jbase = (wid << 10) | lane;  // owned column for k: jbase + (k<<6)

    // Phase 1 (fp32): scores into 16 named registers (coalesced per-wave)
    float f0, f1, f2, f3, f4, f5, f6, f7, f8, f9, f10, f11, f12, f13, f14, f15;
#define INIT_SLOT(K) { \
    const bool m = (pm >> K) & 1u; \
    const float4 sv = s_srcf4[jbase + (K << 6)]; \
    float x0 = sdf0 + sv.x, x1 = sdf1 + sv.y, x2 = sdf2 + sv.z, x3 = sdf3 + sv.w; \
    x0 = (x0 < 0.0f) ? NSLOPEF * x0 : x0; \
    x1 = (x1 < 0.0f) ? NSLOPEF * x1 : x1; \
    x2 = (x2 < 0.0f) ? NSLOPEF * x2 : x2; \
    x3 = (x3 < 0.0f) ? NSLOPEF * x3 : x3; \
    f##K = m ? (0.25f * (x0 + x1 + x2 + x3)) : -INFINITY; }
    FOR16(INIT_SLOT)
#undef INIT_SLOT

    // Phase 2a: parallel dedup (last-write-wins by edge id), thread-per-edge
    if (tid < deg) {
        const int c = ec[tid];
        const int eid = ee[tid];
        bool win = true;
        for (int q = 0; q < deg; ++q)
            if (ec[q] == c && ee[q] > eid) win = false;
        if (win) {
            int p = atomicAdd(&wcnt, 1);
            wcol[p] = c;
            wadd[p] = lam * (double)ewl[tid];
        }
    }
    __syncthreads();

    // Phase 2b (fp32): owner tid = ((c>>10)<<6)|(c&63) applies winner adds
    const int nw = wcnt;
    for (int w = 0; w < nw; ++w) {
        const int c = wcol[w];
        if ((((c >> 10) << 6) | (c & 63)) == tid) {
            const float addf = (float)wadd[w];
            const int kk = (c >> 6) & 15;
#define ADD_SLOT(K) if (kk == K) f##K += addf;
            FOR16(ADD_SLOT)
#undef ADD_SLOT
        }
    }

    // Phase 3a: fp32 monotone keys + per-thread local max
    unsigned int k0, k1, k2, k3, k4, k5, k6, k7, k8, k9, k10, k11, k12, k13, k14, k15;
#define KEY_SLOT(K) { const unsigned u = __float_as_uint(f##K); \
    k##K = u ^ ((unsigned)((int)u >> 31) | 0x80000000u); }
    FOR16(KEY_SLOT)
#undef KEY_SLOT
    unsigned int lmax = k0;
#define LMAX(K) if (k##K > lmax) lmax = k##K;
    FOR16(LMAX)
#undef LMAX

    // Phase 3b: per-wave 15th-largest lane-max via ballot binary search
    unsigned int th = 0;
    for (int b = 31; b >= 0; --b) {
        const unsigned int trial = th | (1u << b);
        unsigned long long m = __ballot(lmax >= trial);
        if (__popcll(m) >= TOPK) th = trial;
    }
    if (lane == 0) wth[wid] = th;
    __syncthreads();
    th = wth[0];
    if (wth[1] > th) th = wth[1];
    if (wth[2] > th) th = wth[2];
    if (wth[3] > th) th = wth[3];
    // Relax by 256 ulp: covers fp32-vs-fp64 ordering divergence near the cut.
    th = (th > 256u) ? (th - 256u) : 0u;

    // Phase 3c: candidate filter (store actual column index)
#define FILT(K) if (k##K >= th) { int p = atomicAdd(&cand_cnt, 1); \
    if (p < CAND_CAP) cand_i[p] = jbase + (K << 6); }
    FOR16(FILT)
#undef FILT
    __syncthreads();

    // Phase 4a: exact fp64 re-score of each candidate (same expression order
    // as the all-fp64 kernel; at most one winner add per column via dedup)
    int C = cand_cnt;
    if (C > CAND_CAP) C = CAND_CAP;
    if (tid < C) {
        const int j = cand_i[tid];
        const double4 sv = s_src4[j];
        double x0 = sd0 + sv.x, x1 = sd1 + sv.y, x2 = sd2 + sv.z, x3 = sd3 + sv.w;
        x0 = (x0 < 0.0) ? NSLOPE * x0 : x0;
        x1 = (x1 < 0.0) ? NSLOPE * x1 : x1;
        x2 = (x2 < 0.0) ? NSLOPE * x2 : x2;
        x3 = (x3 < 0.0) ? NSLOPE * x3 : x3;
        double v = 0.25 * (x0 + x1 + x2 + x3);
        for (int w = 0; w < nw; ++w)
            if (wcol[w] == j) v += wadd[w];
        cand_v[tid] = v;
    }
    __syncthreads();

    // Phase 4b: exact fp64 rank-by-counting among C candidates (unique ranks)
    if (tid < C) {
        const double mv = cand_v[tid];
        const int mi = cand_i[tid];
        int rank = 0;
        for (int q = 0; q < C; ++q) {
            const double qv = cand_v[q];
            const int qi = cand_i[q];
            rank += ((qv > mv) || (qv == mv && qi < mi)) ? 1 : 0;
        }
        if (rank < TOPK) { sorted_v[rank] = mv; sorted_i[rank] = mi; }
    }
    __syncthreads();

    // Phase 5: softmax + store (fp64)
    if (tid < TOPK) exps[tid] = exp(sorted_v[tid] - sorted_v[0]);
    __syncthreads();
    if (tid < TOPK) {
        double s = 0.0;
        for (int t = 0; t < TOPK; ++t) s += exps[t];
        const int NK = N * TOPK;
        const int base = i * TOPK + tid;
        out[base] = (float)sorted_i[tid];      // edge_index row 0: topk column idx
        out[NK + base] = (float)i;             // edge_index row 1: source row
        out[2 * NK + base] = (float)(exps[tid] / s);  // edge_weight (softmax)
    }
}

extern "C" void kernel_launch(void* const* d_in, const int* in_sizes, int n_in,
                              void* d_out, int out_size, void* d_ws, size_t ws_size,
                              hipStream_t stream) {
    const float* emb    = (const float*)d_in[0];
    const float* W      = (const float*)d_in[1];
    const float* att    = (const float*)d_in[2];
    const float* lam    = (const float*)d_in[3];
    const int*   sector = (const int*)d_in[4];
    const int*   active = (const int*)d_in[5];
    const int*   eidx   = (const int*)d_in[6];
    const float* ew     = (const float*)d_in[7];
    float* out = (float*)d_out;

    const int N = in_sizes[5];      // 4096
    const int E = in_sizes[6] / 2;  // 131072

    // workspace layout
    double* wa_dst = (double*)d_ws;                       // 1024 dbl
    double* wa_src = wa_dst + HEADS * H_DIM;              // 1024 dbl
    double* s_dst  = wa_src + HEADS * H_DIM;              // N*4 dbl
    double* s_src  = s_dst + (size_t)N * HEADS;           // N*4 dbl
    float* s_dst_f = (float*)(s_src + (size_t)N * HEADS); // N*4 f32
    float* s_src_f = s_dst_f + (size_t)N * HEADS;         // N*4 f32
    int* cnt       = (int*)(s_src_f + (size_t)N * HEADS); // N int
    unsigned int* abits = (unsigned int*)(cnt + N);       // N/32 uint
    // 16B-align the edge table
    uintptr_t ep = (uintptr_t)(abits + N / 32);
    ep = (ep + 15) & ~(uintptr_t)15;
    int4* etab = (int4*)ep;

    size_t used = (ep - (uintptr_t)d_ws) + 64;
    size_t rem = (ws_size > used) ? (ws_size - used) : 0;
    int cap = (int)(rem / ((size_t)N * 16));
    if (cap > EDGE_CAP_MAX) cap = EDGE_CAP_MAX;
    if (cap < 16) cap = 16;

    const int nb = (E + 255) / 256;   // build blocks (512)
    const int sblocks = N / SROWS;    // s-compute blocks (256)

    prep1_kernel<<<16, 256, 0, stream>>>(W, att, wa_dst, wa_src, cnt, abits, active);
    prep2_kernel<<<sblocks + nb, 256, 0, stream>>>(emb, wa_dst, wa_src, s_dst, s_src,
                                                   s_dst_f, s_src_f, eidx, ew, cnt,
                                                   etab, N, E, cap, sblocks);
    main_kernel<<<N, 256, 0, stream>>>(s_dst, s_src, s_dst_f, s_src_f, sector,
                                       (const unsigned short*)abits, active, lam, cnt,
                                       etab, out, N, cap);
}